// Round 10
// baseline (546.168 us; speedup 1.0000x reference)
//
#include <hip/hip_runtime.h>
#include <hip/hip_fp16.h>
#include <cstdint>

#define BB 4
#define TT 12
#define NN 1000
#define FF 64
#define OO 64
#define SS 4096
#define G3 12288

typedef _Float16 f16x8 __attribute__((ext_vector_type(8)));
typedef float f32x4 __attribute__((ext_vector_type(4)));
typedef _Float16 h2v __attribute__((ext_vector_type(2)));

#if __has_builtin(__builtin_amdgcn_fdot2)
__device__ inline float fdot2(__half2 a, __half2 b, float c) {
    return __builtin_amdgcn_fdot2(*(h2v*)&a, *(h2v*)&b, c, false);
}
#else
__device__ inline float fdot2(__half2 a, __half2 b, float c) {
    float2 fa = __half22float2(a), fb = __half22float2(b);
    return fmaf(fa.x, fb.x, fmaf(fa.y, fb.y, c));
}
#endif

// ---------------------------------------------------------------- init h0 (fp32 + fp16 mirror)
__global__ void k_init_h(const float* __restrict__ h0, float* __restrict__ h_all,
                         __half* __restrict__ h16) {
    int i = blockIdx.x * 256 + threadIdx.x;
    if (i < BB * SS) {
        float v = h0[i & (SS - 1)];
        h_all[i] = v;
        h16[i] = __float2half(v);
    }
}

// ---------------------------------------------------------------- w_hh fp32 -> fp16 (pure streaming, ~6.3 TB/s)
__global__ void k_conv(const float* __restrict__ w, __half* __restrict__ wh) {
    size_t i = ((size_t)blockIdx.x * 256 + threadIdx.x) * 8;
    float4 a = *(const float4*)(w + i);
    float4 b = *(const float4*)(w + i + 4);
    __half2 h0 = __floats2half2_rn(a.x, a.y);
    __half2 h1 = __floats2half2_rn(a.z, a.w);
    __half2 h2 = __floats2half2_rn(b.x, b.y);
    __half2 h3 = __floats2half2_rn(b.z, b.w);
    uint4 o;
    o.x = *(const unsigned*)&h0; o.y = *(const unsigned*)&h1;
    o.z = *(const unsigned*)&h2; o.w = *(const unsigned*)&h3;
    *(uint4*)(wh + i) = o;
}

// ---------------------------------------------------------------- summary = mean_n x
__global__ void k_summary(const float* __restrict__ x, float* __restrict__ summ) {
    int bt = blockIdx.x;
    int f = threadIdx.x & 63, part = threadIdx.x >> 6;
    const float* xp = x + (size_t)bt * NN * FF;
    float s = 0.f;
    for (int n = part; n < NN; n += 4) s += xp[(size_t)n * FF + f];
    __shared__ float red[4][64];
    red[part][f] = s;
    __syncthreads();
    if (part == 0) {
        float tot = red[0][f] + red[1][f] + red[2][f] + red[3][f];
        summ[bt * FF + f] = tot * (1.0f / NN);
    }
}

// ---------------------------------------------------------------- gi = summary @ w_ih^T + b_ih
__global__ void k_gi(const float* __restrict__ summ, const float* __restrict__ w_ih,
                     const float* __restrict__ b_ih, float* __restrict__ gi) {
    int bt = blockIdx.y;
    int j = blockIdx.x * 256 + threadIdx.x;
    __shared__ float sl[64];
    if (threadIdx.x < 64) sl[threadIdx.x] = summ[bt * 64 + threadIdx.x];
    __syncthreads();
    const float* wr = w_ih + (size_t)j * 64;
    float acc = b_ih[j];
#pragma unroll
    for (int k = 0; k < 64; k += 4) {
        float4 w4 = *(const float4*)(wr + k);
        acc += sl[k] * w4.x + sl[k + 1] * w4.y + sl[k + 2] * w4.z + sl[k + 3] * w4.w;
    }
    gi[(size_t)bt * G3 + j] = acc;
}

// ---------------------------------------------------------------- deg only (tier B/C)
__global__ void k_deg(const float* __restrict__ adj, float* __restrict__ invs) {
    int row = blockIdx.x * 4 + (threadIdx.x >> 6);
    int lane = threadIdx.x & 63;
    const float* a = adj + (size_t)row * NN;
    float s = 0.f;
    for (int m = lane * 4; m < NN; m += 256) {
        float4 v = *(const float4*)(a + m);
        s += v.x + v.y + v.z + v.w;
    }
#pragma unroll
    for (int off = 32; off; off >>= 1) s += __shfl_down(s, off);
    if (lane == 0) invs[row] = rsqrtf(fmaxf(s + 1.0f, 1e-8f));
}

// ---------------------------------------------------------------- per-wave deg+conv helper (one adj row)
__device__ inline void degconv_row(const float* __restrict__ adj, float* __restrict__ invs,
                                   __half* __restrict__ adjh, int row, int lane) {
    const float* a = adj + (size_t)row * NN;
    __half* oh = adjh + (size_t)row * NN;
    float s = 0.f;
    for (int m4 = lane; m4 < 250; m4 += 64) {
        float4 v = *(const float4*)(a + m4 * 4);
        s += v.x + v.y + v.z + v.w;
        __half2 p0 = __floats2half2_rn(v.x, v.y);
        __half2 p1 = __floats2half2_rn(v.z, v.w);
        uint2 pk;
        pk.x = *(const unsigned*)&p0; pk.y = *(const unsigned*)&p1;
        *(uint2*)(oh + m4 * 4) = pk;
    }
#pragma unroll
    for (int off = 32; off; off >>= 1) s += __shfl_down(s, off);
    if (lane == 0) invs[row] = rsqrtf(fmaxf(s + 1.0f, 1e-8f));
}

// ---------------------------------------------------------------- fused GRU step v4: 2 rows/wave (j, j+2048), LDS h, deg fused
// grid 1792 x 384. (bx&7)<3 -> deg role (672 blocks, 1/12 adj slice per step).
// GRU role (gid<1024): wave w=(g,p); rows (p, gid*2+g) and (p, gid*2+g+2048).
// h16 staged once in LDS; each h read feeds both row streams (2 independent
// weight streams/wave, 16 k-iters -> deeper memory pipelining).
__global__ __launch_bounds__(384) void k_gstepN(const __half* __restrict__ wh,
                                                const __half* __restrict__ h16_in,
                                                const float* __restrict__ h_in,
                                                const float* __restrict__ b_hh,
                                                const float* __restrict__ gi,
                                                float* __restrict__ h_out,
                                                __half* __restrict__ h16_out,
                                                const float* __restrict__ adj,
                                                float* __restrict__ invs,
                                                __half* __restrict__ adjh, int t) {
    __shared__ __half hl[BB * SS];                   // 32 KB
    __shared__ float sm[6][2][4];
    int bx = blockIdx.x;
    int w = threadIdx.x >> 6, lane = threadIdx.x & 63;
    if ((bx & 7) < 3) {
        int di = (bx >> 3) * 3 + (bx & 7);
        int rl = di * 6 + w;
        if (rl < 4000) degconv_row(adj, invs, adjh, t * 4000 + rl, lane);
        return;
    }
    int gid = bx - ((bx >> 3) * 3 + 3);
    if (gid >= 1024) return;

    for (int i = threadIdx.x; i < 2048; i += 384)
        *(uint4*)(hl + i * 8) = *(const uint4*)(h16_in + i * 8);
    __syncthreads();

    int g = (w * 11) >> 5;                           // w/3: 0,0,0,1,1,1
    int p = w - g * 3;
    int jA = gid * 2 + g;                            // [0,2048)
    const __half* wr0 = wh + ((size_t)p * SS + jA) * SS;
    const __half* wr1 = wh + ((size_t)p * SS + jA + 2048) * SS;
    float a0[4] = {0.f, 0.f, 0.f, 0.f}, a1[4] = {0.f, 0.f, 0.f, 0.f};
#pragma unroll 2
    for (int k0 = 0; k0 < SS; k0 += 512) {
        int k = k0 + lane * 8;
        uint4 u0 = *(const uint4*)(wr0 + k);
        uint4 u1 = *(const uint4*)(wr1 + k);
        const __half2* w0 = (const __half2*)&u0;
        const __half2* w1 = (const __half2*)&u1;
#pragma unroll
        for (int b = 0; b < 4; ++b) {
            uint4 hu = *(const uint4*)(hl + b * SS + k);
            const __half2* hp = (const __half2*)&hu;
#pragma unroll
            for (int q = 0; q < 4; ++q) {
                a0[b] = fdot2(w0[q], hp[q], a0[b]);
                a1[b] = fdot2(w1[q], hp[q], a1[b]);
            }
        }
    }
#pragma unroll
    for (int b = 0; b < 4; ++b)
#pragma unroll
        for (int off = 32; off; off >>= 1) {
            a0[b] += __shfl_down(a0[b], off);
            a1[b] += __shfl_down(a1[b], off);
        }
    if (lane == 0) {
#pragma unroll
        for (int b = 0; b < 4; ++b) { sm[w][0][b] = a0[b]; sm[w][1][b] = a1[b]; }
    }
    __syncthreads();
    if (threadIdx.x < 16) {
        int rr = threadIdx.x >> 2, b = threadIdx.x & 3;
        int gg = rr & 1, sub = rr >> 1;
        int jj = gid * 2 + gg + sub * 2048;
        float hr = sm[gg * 3 + 0][sub][b], hz = sm[gg * 3 + 1][sub][b], hn = sm[gg * 3 + 2][sub][b];
        const float* gib = gi + ((size_t)b * TT + t) * G3;
        float r = 1.f / (1.f + expf(-(gib[jj] + hr + b_hh[jj])));
        float z = 1.f / (1.f + expf(-(gib[SS + jj] + hz + b_hh[SS + jj])));
        float nn = tanhf(gib[2 * SS + jj] + r * (hn + b_hh[2 * SS + jj]));
        float hv = (1.f - z) * nn + z * h_in[(size_t)b * SS + jj];
        h_out[(size_t)b * SS + jj] = hv;
        h16_out[(size_t)b * SS + jj] = __float2half(hv);
    }
}

// ---------------------------------------------------------------- unfused GRU step (tier B), same v4 core
__global__ __launch_bounds__(384) void k_gruN(const __half* __restrict__ wh,
                                              const __half* __restrict__ h16_in,
                                              const float* __restrict__ h_in,
                                              const float* __restrict__ b_hh,
                                              const float* __restrict__ gi,
                                              float* __restrict__ h_out,
                                              __half* __restrict__ h16_out, int t) {
    __shared__ __half hl[BB * SS];
    __shared__ float sm[6][2][4];
    int gid = blockIdx.x;
    int w = threadIdx.x >> 6, lane = threadIdx.x & 63;
    for (int i = threadIdx.x; i < 2048; i += 384)
        *(uint4*)(hl + i * 8) = *(const uint4*)(h16_in + i * 8);
    __syncthreads();
    int g = (w * 11) >> 5;
    int p = w - g * 3;
    int jA = gid * 2 + g;
    const __half* wr0 = wh + ((size_t)p * SS + jA) * SS;
    const __half* wr1 = wh + ((size_t)p * SS + jA + 2048) * SS;
    float a0[4] = {0.f, 0.f, 0.f, 0.f}, a1[4] = {0.f, 0.f, 0.f, 0.f};
#pragma unroll 2
    for (int k0 = 0; k0 < SS; k0 += 512) {
        int k = k0 + lane * 8;
        uint4 u0 = *(const uint4*)(wr0 + k);
        uint4 u1 = *(const uint4*)(wr1 + k);
        const __half2* w0 = (const __half2*)&u0;
        const __half2* w1 = (const __half2*)&u1;
#pragma unroll
        for (int b = 0; b < 4; ++b) {
            uint4 hu = *(const uint4*)(hl + b * SS + k);
            const __half2* hp = (const __half2*)&hu;
#pragma unroll
            for (int q = 0; q < 4; ++q) {
                a0[b] = fdot2(w0[q], hp[q], a0[b]);
                a1[b] = fdot2(w1[q], hp[q], a1[b]);
            }
        }
    }
#pragma unroll
    for (int b = 0; b < 4; ++b)
#pragma unroll
        for (int off = 32; off; off >>= 1) {
            a0[b] += __shfl_down(a0[b], off);
            a1[b] += __shfl_down(a1[b], off);
        }
    if (lane == 0) {
#pragma unroll
        for (int b = 0; b < 4; ++b) { sm[w][0][b] = a0[b]; sm[w][1][b] = a1[b]; }
    }
    __syncthreads();
    if (threadIdx.x < 16) {
        int rr = threadIdx.x >> 2, b = threadIdx.x & 3;
        int gg = rr & 1, sub = rr >> 1;
        int jj = gid * 2 + gg + sub * 2048;
        float hr = sm[gg * 3 + 0][sub][b], hz = sm[gg * 3 + 1][sub][b], hn = sm[gg * 3 + 2][sub][b];
        const float* gib = gi + ((size_t)b * TT + t) * G3;
        float r = 1.f / (1.f + expf(-(gib[jj] + hr + b_hh[jj])));
        float z = 1.f / (1.f + expf(-(gib[SS + jj] + hz + b_hh[SS + jj])));
        float nn = tanhf(gib[2 * SS + jj] + r * (hn + b_hh[2 * SS + jj]));
        float hv = (1.f - z) * nn + z * h_in[(size_t)b * SS + jj];
        h_out[(size_t)b * SS + jj] = hv;
        h16_out[(size_t)b * SS + jj] = __float2half(hv);
    }
}

// ---------------------------------------------------------------- GRU step fp32 (tier C fallback)
__global__ __launch_bounds__(512) void k_gru(const float* __restrict__ w_hh,
                                             const float* __restrict__ b_hh,
                                             const float* __restrict__ gi,
                                             const float* __restrict__ h_in,
                                             float* __restrict__ h_out, int t) {
    __shared__ float hl[BB][SS];
    for (int i = threadIdx.x; i < BB * SS; i += 512)
        hl[i >> 12][i & (SS - 1)] = h_in[i];
    __syncthreads();
    int wave = threadIdx.x >> 6, lane = threadIdx.x & 63;
    int jg = blockIdx.x * 8 + wave;
    const float* r0 = w_hh + (size_t)jg * SS;
    const float* r1 = w_hh + ((size_t)SS + jg) * SS;
    const float* r2 = w_hh + ((size_t)2 * SS + jg) * SS;
    float acc[3][4] = {{0.f}};
    for (int k0 = 0; k0 < SS; k0 += 256) {
        int k = k0 + lane * 4;
        float4 w0 = *(const float4*)(r0 + k);
        float4 w1 = *(const float4*)(r1 + k);
        float4 w2 = *(const float4*)(r2 + k);
#pragma unroll
        for (int b = 0; b < 4; ++b) {
            float4 hv = *(const float4*)&hl[b][k];
            acc[0][b] += w0.x * hv.x + w0.y * hv.y + w0.z * hv.z + w0.w * hv.w;
            acc[1][b] += w1.x * hv.x + w1.y * hv.y + w1.z * hv.z + w1.w * hv.w;
            acc[2][b] += w2.x * hv.x + w2.y * hv.y + w2.z * hv.z + w2.w * hv.w;
        }
    }
#pragma unroll
    for (int p = 0; p < 3; ++p)
#pragma unroll
        for (int b = 0; b < 4; ++b)
#pragma unroll
            for (int off = 32; off; off >>= 1)
                acc[p][b] += __shfl_down(acc[p][b], off);
    if (lane == 0) {
        float br = b_hh[jg], bz = b_hh[SS + jg], bn = b_hh[2 * SS + jg];
#pragma unroll
        for (int b = 0; b < 4; ++b) {
            const float* gib = gi + ((size_t)b * TT + t) * G3;
            float r = 1.f / (1.f + expf(-(gib[jg] + acc[0][b] + br)));
            float z = 1.f / (1.f + expf(-(gib[SS + jg] + acc[1][b] + bz)));
            float nn = tanhf(gib[2 * SS + jg] + r * (acc[2][b] + bn));
            h_out[(size_t)b * SS + jg] = (1.f - z) * nn + z * hl[b][jg];
        }
    }
}

// ---------------------------------------------------------------- support (tier A): sp fp32 + spT fp16 transposed
__global__ __launch_bounds__(256) void k_support2(const float* __restrict__ x,
                                                  const float* __restrict__ h_all,
                                                  const float* __restrict__ invs,
                                                  float* __restrict__ sp,
                                                  __half* __restrict__ spT) {
    int nt = blockIdx.x, b = blockIdx.y, t = blockIdx.z;
    int n0 = nt * 64;
    int o = threadIdx.x & 63, g = threadIdx.x >> 6;
    __shared__ float wl[64][64];
    __shared__ float xl[64][64];
    __shared__ __half tl[64][72];
    for (int i = threadIdx.x; i < 64 * 72 / 2; i += 256)
        *(__half2*)&tl[0][i * 2] = __half2{};
    const float* h = h_all + ((size_t)(t + 1) * BB + b) * SS;
    for (int i = threadIdx.x; i < SS; i += 256) wl[i >> 6][i & 63] = h[i];
    const float* xp = x + ((size_t)(b * TT + t) * NN + n0) * FF;
    for (int i = threadIdx.x; i < 64 * 64; i += 256) {
        int nl = i >> 6, f = i & 63;
        xl[nl][f] = (n0 + nl < NN) ? xp[(size_t)nl * FF + f] : 0.f;
    }
    __syncthreads();
    size_t bt = (size_t)b * TT + t;
    for (int nl = g; nl < 64; nl += 4) {
        int n = n0 + nl;
        if (n >= NN) break;
        float acc = 0.f;
#pragma unroll
        for (int f = 0; f < 64; ++f) acc += xl[nl][f] * wl[f][o];
        size_t idx = bt * NN + n;
        float v = acc * invs[idx];
        sp[idx * OO + o] = v;
        tl[o][nl] = __float2half(v);
    }
    __syncthreads();
    int orow = threadIdx.x >> 2, seg = threadIdx.x & 3;
    uint4 lo = *(const uint4*)&tl[orow][seg * 16];
    uint4 hi = *(const uint4*)&tl[orow][seg * 16 + 8];
    __half* dst = spT + ((bt * 64 + orow) * 1024 + n0 + seg * 16);
    *(uint4*)dst = lo;
    *(uint4*)(dst + 8) = hi;
}

// ---------------------------------------------------------------- support (tier B/C): sp fp32 only
__global__ __launch_bounds__(256) void k_support(const float* __restrict__ x,
                                                 const float* __restrict__ h_all,
                                                 const float* __restrict__ invs,
                                                 float* __restrict__ sp) {
    int nt = blockIdx.x, b = blockIdx.y, t = blockIdx.z;
    int n0 = nt * 64;
    int o = threadIdx.x & 63, g = threadIdx.x >> 6;
    __shared__ float wl[64][64];
    __shared__ float xl[64][64];
    const float* h = h_all + ((size_t)(t + 1) * BB + b) * SS;
    for (int i = threadIdx.x; i < SS; i += 256) wl[i >> 6][i & 63] = h[i];
    const float* xp = x + ((size_t)(b * TT + t) * NN + n0) * FF;
    for (int i = threadIdx.x; i < 64 * 64; i += 256) {
        int nl = i >> 6, f = i & 63;
        xl[nl][f] = (n0 + nl < NN) ? xp[(size_t)nl * FF + f] : 0.f;
    }
    __syncthreads();
    for (int nl = g; nl < 64; nl += 4) {
        int n = n0 + nl;
        if (n >= NN) break;
        float acc = 0.f;
#pragma unroll
        for (int f = 0; f < 64; ++f) acc += xl[nl][f] * wl[f][o];
        size_t idx = ((size_t)(b * TT + t) * NN + n);
        sp[idx * OO + o] = acc * invs[idx];
    }
}

// ---------------------------------------------------------------- k_out MFMA (tier A)
__global__ __launch_bounds__(256) void k_out_mfma(const __half* __restrict__ adjh,
                                                  const __half* __restrict__ spT,
                                                  const float* __restrict__ sp32,
                                                  const float* __restrict__ invs,
                                                  const float* __restrict__ bias,
                                                  float* __restrict__ out) {
    int nb = blockIdx.x, b = blockIdx.y, t = blockIdx.z;
    int n0 = nb * 64;
    size_t bt = (size_t)b * TT + t;
    __shared__ alignas(16) __half Al[64 * 64];
    __shared__ alignas(16) __half Bl[64 * 64];
    int wave = threadIdx.x >> 6, lane = threadIdx.x & 63;
    const __half* Ag = adjh + bt * (size_t)(NN * NN);
    const __half* Bg = spT + bt * (size_t)(64 * 1024);
    f32x4 acc[4] = {};

    for (int ch = 0; ch < 16; ++ch) {
        __syncthreads();
#pragma unroll
        for (int rep = 0; rep < 2; ++rep) {
            int idx = threadIdx.x + rep * 256;
            int r = idx >> 3, g = idx & 7;
            int gg = ch * 8 + g;
            uint4 va = {0, 0, 0, 0};
            if (n0 + r < NN && gg < 125)
                va = *(const uint4*)(Ag + (size_t)(n0 + r) * NN + gg * 8);
            *(uint4*)&Al[(r * 8 + (g ^ (r & 7))) * 8] = va;
            uint4 vb = *(const uint4*)(Bg + (size_t)r * 1024 + gg * 8);
            *(uint4*)&Bl[(r * 8 + (g ^ (r & 7))) * 8] = vb;
        }
        __syncthreads();
#pragma unroll
        for (int kc = 0; kc < 2; ++kc) {
            int ar = wave * 16 + (lane & 15);
            int ag = kc * 4 + (lane >> 4);
            f16x8 av = *(const f16x8*)&Al[(ar * 8 + (ag ^ (ar & 7))) * 8];
#pragma unroll
            for (int ct = 0; ct < 4; ++ct) {
                int br = ct * 16 + (lane & 15);
                f16x8 bv = *(const f16x8*)&Bl[(br * 8 + (ag ^ (br & 7))) * 8];
                acc[ct] = __builtin_amdgcn_mfma_f32_16x16x32_f16(av, bv, acc[ct], 0, 0, 0);
            }
        }
    }
#pragma unroll
    for (int ct = 0; ct < 4; ++ct) {
        int o = ct * 16 + (lane & 15);
        float bo = bias[o];
#pragma unroll
        for (int r = 0; r < 4; ++r) {
            int n = n0 + wave * 16 + (lane >> 4) * 4 + r;
            if (n < NN) {
                float iv = invs[bt * NN + n];
                float d = sp32[(bt * NN + n) * OO + o];
                out[(bt * NN + n) * OO + o] = fmaxf(iv * (acc[ct][r] + d) + bo, 0.f);
            }
        }
    }
}

// ---------------------------------------------------------------- k_out fp32 (tier B/C)
__global__ __launch_bounds__(256) void k_out(const float* __restrict__ adj,
                                             const float* __restrict__ sp,
                                             const float* __restrict__ invs,
                                             const float* __restrict__ bias,
                                             float* __restrict__ out) {
    int nb = blockIdx.x, b = blockIdx.y, t = blockIdx.z;
    int n0 = nb * 64;
    int cq = threadIdx.x & 15;
    int rg = threadIdx.x >> 4;
    __shared__ float spl[64][64];
    __shared__ float al[64][68];
    size_t bt = (size_t)b * TT + t;
    const float* adjp = adj + bt * (size_t)NN * NN;
    const float* spp  = sp  + bt * (size_t)NN * OO;
    float4 a0 = {0,0,0,0}, a1 = {0,0,0,0}, a2 = {0,0,0,0}, a3 = {0,0,0,0};
    for (int m0 = 0; m0 < NN; m0 += 64) {
        __syncthreads();
        for (int i = threadIdx.x; i < 1024; i += 256) {
            int r = i >> 4, c4 = (i & 15) * 4;
            int m = m0 + r;
            float4 v = (m < NN) ? *(const float4*)&spp[(size_t)m * OO + c4] : float4{0,0,0,0};
            *(float4*)&spl[r][c4] = v;
        }
        for (int i = threadIdx.x; i < 1024; i += 256) {
            int r = i >> 4, c4 = (i & 15) * 4;
            int n = n0 + r, m = m0 + c4;
            float4 v = (n < NN && m < NN) ? *(const float4*)&adjp[(size_t)n * NN + m] : float4{0,0,0,0};
            *(float4*)&al[r][c4] = v;
        }
        __syncthreads();
#pragma unroll 4
        for (int mm = 0; mm < 64; mm += 4) {
            float4 s0 = *(const float4*)&spl[mm + 0][cq * 4];
            float4 s1 = *(const float4*)&spl[mm + 1][cq * 4];
            float4 s2 = *(const float4*)&spl[mm + 2][cq * 4];
            float4 s3 = *(const float4*)&spl[mm + 3][cq * 4];
            float4 r0 = *(const float4*)&al[rg * 4 + 0][mm];
            float4 r1 = *(const float4*)&al[rg * 4 + 1][mm];
            float4 r2 = *(const float4*)&al[rg * 4 + 2][mm];
            float4 r3 = *(const float4*)&al[rg * 4 + 3][mm];
            a0.x += r0.x*s0.x + r0.y*s1.x + r0.z*s2.x + r0.w*s3.x;
            a0.y += r0.x*s0.y + r0.y*s1.y + r0.z*s2.y + r0.w*s3.y;
            a0.z += r0.x*s0.z + r0.y*s1.z + r0.z*s2.z + r0.w*s3.z;
            a0.w += r0.x*s0.w + r0.y*s1.w + r0.z*s2.w + r0.w*s3.w;
            a1.x += r1.x*s0.x + r1.y*s1.x + r1.z*s2.x + r1.w*s3.x;
            a1.y += r1.x*s0.y + r1.y*s1.y + r1.z*s2.y + r1.w*s3.y;
            a1.z += r1.x*s0.z + r1.y*s1.z + r1.z*s2.z + r1.w*s3.z;
            a1.w += r1.x*s0.w + r1.y*s1.w + r1.z*s2.w + r1.w*s3.w;
            a2.x += r2.x*s0.x + r2.y*s1.x + r2.z*s2.x + r2.w*s3.x;
            a2.y += r2.x*s0.y + r2.y*s1.y + r2.z*s2.y + r2.w*s3.y;
            a2.z += r2.x*s0.z + r2.y*s1.z + r2.z*s2.z + r2.w*s3.z;
            a2.w += r2.x*s0.w + r2.y*s1.w + r2.z*s2.w + r2.w*s3.w;
            a3.x += r3.x*s0.x + r3.y*s1.x + r3.z*s2.x + r3.w*s3.x;
            a3.y += r3.x*s0.y + r3.y*s1.y + r3.z*s2.y + r3.w*s3.y;
            a3.z += r3.x*s0.z + r3.y*s1.z + r3.z*s2.z + r3.w*s3.z;
            a3.w += r3.x*s0.w + r3.y*s1.w + r3.z*s2.w + r3.w*s3.w;
        }
    }
    float4 bias4 = *(const float4*)&bias[cq * 4];
    float4 accs[4] = {a0, a1, a2, a3};
#pragma unroll
    for (int i = 0; i < 4; ++i) {
        int n = n0 + rg * 4 + i;
        if (n < NN) {
            float iv = invs[bt * NN + n];
            float4 d = *(const float4*)&spp[(size_t)n * OO + cq * 4];
            float4 v;
            v.x = fmaxf(iv * (accs[i].x + d.x) + bias4.x, 0.f);
            v.y = fmaxf(iv * (accs[i].y + d.y) + bias4.y, 0.f);
            v.z = fmaxf(iv * (accs[i].z + d.z) + bias4.z, 0.f);
            v.w = fmaxf(iv * (accs[i].w + d.w) + bias4.w, 0.f);
            *(float4*)&out[(bt * NN + n) * OO + cq * 4] = v;
        }
    }
}

// ---------------------------------------------------------------- launch
extern "C" void kernel_launch(void* const* d_in, const int* in_sizes, int n_in,
                              void* d_out, int out_size, void* d_ws, size_t ws_size,
                              hipStream_t stream) {
    const float* x    = (const float*)d_in[0];
    const float* adj  = (const float*)d_in[1];
    const float* w_ih = (const float*)d_in[2];
    const float* w_hh = (const float*)d_in[3];
    const float* b_ih = (const float*)d_in[4];
    const float* b_hh = (const float*)d_in[5];
    const float* h0   = (const float*)d_in[6];
    const float* bias = (const float*)d_in[7];
    float* out = (float*)d_out;
    float* ws = (float*)d_ws;

    float* invs  = ws;                          // 48000
    float* summ  = invs + 48000;                // 3072
    float* gi    = summ + 3072;                 // 589824
    float* h_all = gi + 589824;                 // 13 * 16384 = 212992
    float* sp    = h_all + 212992;              // 3072000
    const size_t base_f = 3925888;              // floats
    __half* wh    = (__half*)(ws + base_f);         // 50,331,648 halves (100.7 MB)
    __half* h16   = wh + 50331648ull;               // 13 * 16384 halves
    __half* adjh  = h16 + 212992ull;                // 48,000,000 halves (96 MB)
    __half* spT   = adjh + 48000000ull;             // 3,145,728 halves (6.3 MB)
    const size_t need_B = base_f * 4 + (50331648ull + 212992ull) * 2;
    const size_t need_A = need_B + (48000000ull + 3145728ull) * 2;
    bool tierA = ws_size >= need_A;
    bool tierB = ws_size >= need_B;

    k_init_h<<<64, 256, 0, stream>>>(h0, h_all, h16);
    k_summary<<<48, 256, 0, stream>>>(x, summ);
    k_gi<<<dim3(48, 48), 256, 0, stream>>>(summ, w_ih, b_ih, gi);
    if (tierA) {
        k_conv<<<24576, 256, 0, stream>>>(w_hh, wh);       // pure streaming fp32->fp16
        for (int t = 0; t < TT; ++t)
            k_gstepN<<<1792, 384, 0, stream>>>(wh,
                                               h16 + (size_t)t * BB * SS,
                                               h_all + (size_t)t * BB * SS,
                                               b_hh, gi,
                                               h_all + (size_t)(t + 1) * BB * SS,
                                               h16 + (size_t)(t + 1) * BB * SS,
                                               adj, invs, adjh, t);
        k_support2<<<dim3(16, 4, 12), 256, 0, stream>>>(x, h_all, invs, sp, spT);
        k_out_mfma<<<dim3(16, 4, 12), 256, 0, stream>>>(adjh, spT, sp, invs, bias, out);
    } else if (tierB) {
        k_conv<<<24576, 256, 0, stream>>>(w_hh, wh);
        for (int t = 0; t < TT; ++t)
            k_gruN<<<1024, 384, 0, stream>>>(wh,
                                             h16 + (size_t)t * BB * SS,
                                             h_all + (size_t)t * BB * SS,
                                             b_hh, gi,
                                             h_all + (size_t)(t + 1) * BB * SS,
                                             h16 + (size_t)(t + 1) * BB * SS, t);
        k_deg<<<12000, 256, 0, stream>>>(adj, invs);
        k_support<<<dim3(16, 4, 12), 256, 0, stream>>>(x, h_all, invs, sp);
        k_out<<<dim3(16, 4, 12), 256, 0, stream>>>(adj, sp, invs, bias, out);
    } else {
        for (int t = 0; t < TT; ++t)
            k_gru<<<512, 512, 0, stream>>>(w_hh, b_hh, gi,
                                           h_all + (size_t)t * BB * SS,
                                           h_all + (size_t)(t + 1) * BB * SS, t);
        k_deg<<<12000, 256, 0, stream>>>(adj, invs);
        k_support<<<dim3(16, 4, 12), 256, 0, stream>>>(x, h_all, invs, sp);
        k_out<<<dim3(16, 4, 12), 256, 0, stream>>>(adj, sp, invs, bias, out);
    }
}

// Round 11
// 506.933 us; speedup vs baseline: 1.0774x; 1.0774x over previous
//
#include <hip/hip_runtime.h>
#include <hip/hip_fp16.h>
#include <cstdint>

#define BB 4
#define TT 12
#define NN 1000
#define FF 64
#define OO 64
#define SS 4096
#define G3 12288

typedef _Float16 f16x8 __attribute__((ext_vector_type(8)));
typedef float f32x4 __attribute__((ext_vector_type(4)));
typedef _Float16 h2v __attribute__((ext_vector_type(2)));

#if __has_builtin(__builtin_amdgcn_fdot2)
__device__ inline float fdot2(__half2 a, __half2 b, float c) {
    return __builtin_amdgcn_fdot2(*(h2v*)&a, *(h2v*)&b, c, false);
}
#else
__device__ inline float fdot2(__half2 a, __half2 b, float c) {
    float2 fa = __half22float2(a), fb = __half22float2(b);
    return fmaf(fa.x, fb.x, fmaf(fa.y, fb.y, c));
}
#endif

// ---------------------------------------------------------------- init h0 (fp32 + fp16 mirror)
__global__ void k_init_h(const float* __restrict__ h0, float* __restrict__ h_all,
                         __half* __restrict__ h16) {
    int i = blockIdx.x * 256 + threadIdx.x;
    if (i < BB * SS) {
        float v = h0[i & (SS - 1)];
        h_all[i] = v;
        h16[i] = __float2half(v);
    }
}

// ---------------------------------------------------------------- w_hh fp32 -> fp16 (block-linear stream, ~6.3 TB/s)
__global__ void k_conv(const float* __restrict__ w, __half* __restrict__ wh) {
    size_t i = ((size_t)blockIdx.x * 256 + threadIdx.x) * 8;
    float4 a = *(const float4*)(w + i);
    float4 b = *(const float4*)(w + i + 4);
    __half2 h0 = __floats2half2_rn(a.x, a.y);
    __half2 h1 = __floats2half2_rn(a.z, a.w);
    __half2 h2 = __floats2half2_rn(b.x, b.y);
    __half2 h3 = __floats2half2_rn(b.z, b.w);
    uint4 o;
    o.x = *(const unsigned*)&h0; o.y = *(const unsigned*)&h1;
    o.z = *(const unsigned*)&h2; o.w = *(const unsigned*)&h3;
    *(uint4*)(wh + i) = o;
}

// ---------------------------------------------------------------- summary = mean_n x
__global__ void k_summary(const float* __restrict__ x, float* __restrict__ summ) {
    int bt = blockIdx.x;
    int f = threadIdx.x & 63, part = threadIdx.x >> 6;
    const float* xp = x + (size_t)bt * NN * FF;
    float s = 0.f;
    for (int n = part; n < NN; n += 4) s += xp[(size_t)n * FF + f];
    __shared__ float red[4][64];
    red[part][f] = s;
    __syncthreads();
    if (part == 0) {
        float tot = red[0][f] + red[1][f] + red[2][f] + red[3][f];
        summ[bt * FF + f] = tot * (1.0f / NN);
    }
}

// ---------------------------------------------------------------- gi = summary @ w_ih^T + b_ih
__global__ void k_gi(const float* __restrict__ summ, const float* __restrict__ w_ih,
                     const float* __restrict__ b_ih, float* __restrict__ gi) {
    int bt = blockIdx.y;
    int j = blockIdx.x * 256 + threadIdx.x;
    __shared__ float sl[64];
    if (threadIdx.x < 64) sl[threadIdx.x] = summ[bt * 64 + threadIdx.x];
    __syncthreads();
    const float* wr = w_ih + (size_t)j * 64;
    float acc = b_ih[j];
#pragma unroll
    for (int k = 0; k < 64; k += 4) {
        float4 w4 = *(const float4*)(wr + k);
        acc += sl[k] * w4.x + sl[k + 1] * w4.y + sl[k + 2] * w4.z + sl[k + 3] * w4.w;
    }
    gi[(size_t)bt * G3 + j] = acc;
}

// ---------------------------------------------------------------- deg only (tier B/C)
__global__ void k_deg(const float* __restrict__ adj, float* __restrict__ invs) {
    int row = blockIdx.x * 4 + (threadIdx.x >> 6);
    int lane = threadIdx.x & 63;
    const float* a = adj + (size_t)row * NN;
    float s = 0.f;
    for (int m = lane * 4; m < NN; m += 256) {
        float4 v = *(const float4*)(a + m);
        s += v.x + v.y + v.z + v.w;
    }
#pragma unroll
    for (int off = 32; off; off >>= 1) s += __shfl_down(s, off);
    if (lane == 0) invs[row] = rsqrtf(fmaxf(s + 1.0f, 1e-8f));
}

// ---------------------------------------------------------------- per-wave deg+conv helper (one adj row)
__device__ inline void degconv_row(const float* __restrict__ adj, float* __restrict__ invs,
                                   __half* __restrict__ adjh, int row, int lane) {
    const float* a = adj + (size_t)row * NN;
    __half* oh = adjh + (size_t)row * NN;
    float s = 0.f;
    for (int m4 = lane; m4 < 250; m4 += 64) {
        float4 v = *(const float4*)(a + m4 * 4);
        s += v.x + v.y + v.z + v.w;
        __half2 p0 = __floats2half2_rn(v.x, v.y);
        __half2 p1 = __floats2half2_rn(v.z, v.w);
        uint2 pk;
        pk.x = *(const unsigned*)&p0; pk.y = *(const unsigned*)&p1;
        *(uint2*)(oh + m4 * 4) = pk;
    }
#pragma unroll
    for (int off = 32; off; off >>= 1) s += __shfl_down(s, off);
    if (lane == 0) invs[row] = rsqrtf(fmaxf(s + 1.0f, 1e-8f));
}

// ---------------------------------------------------------------- fused GRU step (R7 v2 structure, all steps fp16)
// grid 2715: blocks {0,4,...,2664} (667) stream 1/12 of adj (deg+fp16 conv);
// the other 2048 blocks run the GRU step (6 waves = 2 gates x 3 parts, h16 in LDS).
__global__ __launch_bounds__(384) void k_gstepN(const __half* __restrict__ wh,
                                                const __half* __restrict__ h16_in,
                                                const float* __restrict__ h_in,
                                                const float* __restrict__ b_hh,
                                                const float* __restrict__ gi,
                                                float* __restrict__ h_out,
                                                __half* __restrict__ h16_out,
                                                const float* __restrict__ adj,
                                                float* __restrict__ invs,
                                                __half* __restrict__ adjh, int t) {
    __shared__ __half hl[BB * SS];                   // 32 KB
    __shared__ float sm[6][4];
    int bx = blockIdx.x;
    int w = threadIdx.x >> 6, lane = threadIdx.x & 63;
    bool isdeg = (bx < 2668) && ((bx & 3) == 0);
    if (isdeg) {
        int rl = (bx >> 2) * 6 + w;
        if (rl < 4000) degconv_row(adj, invs, adjh, t * 4000 + rl, lane);
        return;
    }
    for (int i = threadIdx.x; i < 2048; i += 384)
        *(uint4*)(hl + i * 8) = *(const uint4*)(h16_in + i * 8);
    __syncthreads();

    int nd = (bx < 2668) ? ((bx >> 2) + 1) : 667;    // degconv blocks before bx
    int gid = bx - nd;                               // 0..2047
    int g = (w * 11) >> 5;                           // w/3
    int p = w - g * 3;
    int j = gid * 2 + g;
    const __half* wrow = wh + ((size_t)p * SS + j) * SS;
    float acc[4] = {0.f, 0.f, 0.f, 0.f};
#pragma unroll 2
    for (int k0 = 0; k0 < SS; k0 += 512) {
        int k = k0 + lane * 8;
        uint4 wv = *(const uint4*)(wrow + k);
        const __half2* wp = (const __half2*)&wv;
#pragma unroll
        for (int b = 0; b < 4; ++b) {
            uint4 hu = *(const uint4*)(hl + b * SS + k);
            const __half2* hp = (const __half2*)&hu;
#pragma unroll
            for (int q = 0; q < 4; ++q)
                acc[b] = fdot2(wp[q], hp[q], acc[b]);
        }
    }
#pragma unroll
    for (int b = 0; b < 4; ++b)
#pragma unroll
        for (int off = 32; off; off >>= 1)
            acc[b] += __shfl_down(acc[b], off);
    if (lane == 0) {
        sm[w][0] = acc[0]; sm[w][1] = acc[1]; sm[w][2] = acc[2]; sm[w][3] = acc[3];
    }
    __syncthreads();
    if (threadIdx.x < 8) {
        int gg = threadIdx.x >> 2, b = threadIdx.x & 3;
        int jj = gid * 2 + gg;
        float hr = sm[gg * 3 + 0][b], hz = sm[gg * 3 + 1][b], hn = sm[gg * 3 + 2][b];
        const float* gib = gi + ((size_t)b * TT + t) * G3;
        float r = 1.f / (1.f + expf(-(gib[jj] + hr + b_hh[jj])));
        float z = 1.f / (1.f + expf(-(gib[SS + jj] + hz + b_hh[SS + jj])));
        float nn = tanhf(gib[2 * SS + jj] + r * (hn + b_hh[2 * SS + jj]));
        float hv = (1.f - z) * nn + z * h_in[(size_t)b * SS + jj];
        h_out[(size_t)b * SS + jj] = hv;
        h16_out[(size_t)b * SS + jj] = __float2half(hv);
    }
}

// ---------------------------------------------------------------- unfused GRU step (tier B)
__global__ __launch_bounds__(384) void k_gruN(const __half* __restrict__ wh,
                                              const __half* __restrict__ h16_in,
                                              const float* __restrict__ h_in,
                                              const float* __restrict__ b_hh,
                                              const float* __restrict__ gi,
                                              float* __restrict__ h_out,
                                              __half* __restrict__ h16_out, int t) {
    __shared__ __half hl[BB * SS];
    __shared__ float sm[6][4];
    int w = threadIdx.x >> 6, lane = threadIdx.x & 63;
    for (int i = threadIdx.x; i < 2048; i += 384)
        *(uint4*)(hl + i * 8) = *(const uint4*)(h16_in + i * 8);
    __syncthreads();
    int g = (w * 11) >> 5;
    int p = w - g * 3;
    int j = blockIdx.x * 2 + g;
    const __half* wrow = wh + ((size_t)p * SS + j) * SS;
    float acc[4] = {0.f, 0.f, 0.f, 0.f};
#pragma unroll 2
    for (int k0 = 0; k0 < SS; k0 += 512) {
        int k = k0 + lane * 8;
        uint4 wv = *(const uint4*)(wrow + k);
        const __half2* wp = (const __half2*)&wv;
#pragma unroll
        for (int b = 0; b < 4; ++b) {
            uint4 hu = *(const uint4*)(hl + b * SS + k);
            const __half2* hp = (const __half2*)&hu;
#pragma unroll
            for (int q = 0; q < 4; ++q)
                acc[b] = fdot2(wp[q], hp[q], acc[b]);
        }
    }
#pragma unroll
    for (int b = 0; b < 4; ++b)
#pragma unroll
        for (int off = 32; off; off >>= 1)
            acc[b] += __shfl_down(acc[b], off);
    if (lane == 0) {
        sm[w][0] = acc[0]; sm[w][1] = acc[1]; sm[w][2] = acc[2]; sm[w][3] = acc[3];
    }
    __syncthreads();
    if (threadIdx.x < 8) {
        int gg = threadIdx.x >> 2, b = threadIdx.x & 3;
        int jj = blockIdx.x * 2 + gg;
        float hr = sm[gg * 3 + 0][b], hz = sm[gg * 3 + 1][b], hn = sm[gg * 3 + 2][b];
        const float* gib = gi + ((size_t)b * TT + t) * G3;
        float r = 1.f / (1.f + expf(-(gib[jj] + hr + b_hh[jj])));
        float z = 1.f / (1.f + expf(-(gib[SS + jj] + hz + b_hh[SS + jj])));
        float nn = tanhf(gib[2 * SS + jj] + r * (hn + b_hh[2 * SS + jj]));
        float hv = (1.f - z) * nn + z * h_in[(size_t)b * SS + jj];
        h_out[(size_t)b * SS + jj] = hv;
        h16_out[(size_t)b * SS + jj] = __float2half(hv);
    }
}

// ---------------------------------------------------------------- GRU step fp32 (tier C fallback)
__global__ __launch_bounds__(512) void k_gru(const float* __restrict__ w_hh,
                                             const float* __restrict__ b_hh,
                                             const float* __restrict__ gi,
                                             const float* __restrict__ h_in,
                                             float* __restrict__ h_out, int t) {
    __shared__ float hl[BB][SS];
    for (int i = threadIdx.x; i < BB * SS; i += 512)
        hl[i >> 12][i & (SS - 1)] = h_in[i];
    __syncthreads();
    int wave = threadIdx.x >> 6, lane = threadIdx.x & 63;
    int jg = blockIdx.x * 8 + wave;
    const float* r0 = w_hh + (size_t)jg * SS;
    const float* r1 = w_hh + ((size_t)SS + jg) * SS;
    const float* r2 = w_hh + ((size_t)2 * SS + jg) * SS;
    float acc[3][4] = {{0.f}};
    for (int k0 = 0; k0 < SS; k0 += 256) {
        int k = k0 + lane * 4;
        float4 w0 = *(const float4*)(r0 + k);
        float4 w1 = *(const float4*)(r1 + k);
        float4 w2 = *(const float4*)(r2 + k);
#pragma unroll
        for (int b = 0; b < 4; ++b) {
            float4 hv = *(const float4*)&hl[b][k];
            acc[0][b] += w0.x * hv.x + w0.y * hv.y + w0.z * hv.z + w0.w * hv.w;
            acc[1][b] += w1.x * hv.x + w1.y * hv.y + w1.z * hv.z + w1.w * hv.w;
            acc[2][b] += w2.x * hv.x + w2.y * hv.y + w2.z * hv.z + w2.w * hv.w;
        }
    }
#pragma unroll
    for (int p = 0; p < 3; ++p)
#pragma unroll
        for (int b = 0; b < 4; ++b)
#pragma unroll
            for (int off = 32; off; off >>= 1)
                acc[p][b] += __shfl_down(acc[p][b], off);
    if (lane == 0) {
        float br = b_hh[jg], bz = b_hh[SS + jg], bn = b_hh[2 * SS + jg];
#pragma unroll
        for (int b = 0; b < 4; ++b) {
            const float* gib = gi + ((size_t)b * TT + t) * G3;
            float r = 1.f / (1.f + expf(-(gib[jg] + acc[0][b] + br)));
            float z = 1.f / (1.f + expf(-(gib[SS + jg] + acc[1][b] + bz)));
            float nn = tanhf(gib[2 * SS + jg] + r * (acc[2][b] + bn));
            h_out[(size_t)b * SS + jg] = (1.f - z) * nn + z * hl[b][jg];
        }
    }
}

// ---------------------------------------------------------------- support (tier A): sp fp32 + spT fp16 transposed
__global__ __launch_bounds__(256) void k_support2(const float* __restrict__ x,
                                                  const float* __restrict__ h_all,
                                                  const float* __restrict__ invs,
                                                  float* __restrict__ sp,
                                                  __half* __restrict__ spT) {
    int nt = blockIdx.x, b = blockIdx.y, t = blockIdx.z;
    int n0 = nt * 64;
    int o = threadIdx.x & 63, g = threadIdx.x >> 6;
    __shared__ float wl[64][64];
    __shared__ float xl[64][64];
    __shared__ __half tl[64][72];
    for (int i = threadIdx.x; i < 64 * 72 / 2; i += 256)
        *(__half2*)&tl[0][i * 2] = __half2{};
    const float* h = h_all + ((size_t)(t + 1) * BB + b) * SS;
    for (int i = threadIdx.x; i < SS; i += 256) wl[i >> 6][i & 63] = h[i];
    const float* xp = x + ((size_t)(b * TT + t) * NN + n0) * FF;
    for (int i = threadIdx.x; i < 64 * 64; i += 256) {
        int nl = i >> 6, f = i & 63;
        xl[nl][f] = (n0 + nl < NN) ? xp[(size_t)nl * FF + f] : 0.f;
    }
    __syncthreads();
    size_t bt = (size_t)b * TT + t;
    for (int nl = g; nl < 64; nl += 4) {
        int n = n0 + nl;
        if (n >= NN) break;
        float acc = 0.f;
#pragma unroll
        for (int f = 0; f < 64; ++f) acc += xl[nl][f] * wl[f][o];
        size_t idx = bt * NN + n;
        float v = acc * invs[idx];
        sp[idx * OO + o] = v;
        tl[o][nl] = __float2half(v);
    }
    __syncthreads();
    int orow = threadIdx.x >> 2, seg = threadIdx.x & 3;
    uint4 lo = *(const uint4*)&tl[orow][seg * 16];
    uint4 hi = *(const uint4*)&tl[orow][seg * 16 + 8];
    __half* dst = spT + ((bt * 64 + orow) * 1024 + n0 + seg * 16);
    *(uint4*)dst = lo;
    *(uint4*)(dst + 8) = hi;
}

// ---------------------------------------------------------------- support (tier B/C): sp fp32 only
__global__ __launch_bounds__(256) void k_support(const float* __restrict__ x,
                                                 const float* __restrict__ h_all,
                                                 const float* __restrict__ invs,
                                                 float* __restrict__ sp) {
    int nt = blockIdx.x, b = blockIdx.y, t = blockIdx.z;
    int n0 = nt * 64;
    int o = threadIdx.x & 63, g = threadIdx.x >> 6;
    __shared__ float wl[64][64];
    __shared__ float xl[64][64];
    const float* h = h_all + ((size_t)(t + 1) * BB + b) * SS;
    for (int i = threadIdx.x; i < SS; i += 256) wl[i >> 6][i & 63] = h[i];
    const float* xp = x + ((size_t)(b * TT + t) * NN + n0) * FF;
    for (int i = threadIdx.x; i < 64 * 64; i += 256) {
        int nl = i >> 6, f = i & 63;
        xl[nl][f] = (n0 + nl < NN) ? xp[(size_t)nl * FF + f] : 0.f;
    }
    __syncthreads();
    for (int nl = g; nl < 64; nl += 4) {
        int n = n0 + nl;
        if (n >= NN) break;
        float acc = 0.f;
#pragma unroll
        for (int f = 0; f < 64; ++f) acc += xl[nl][f] * wl[f][o];
        size_t idx = ((size_t)(b * TT + t) * NN + n);
        sp[idx * OO + o] = acc * invs[idx];
    }
}

// ---------------------------------------------------------------- k_out MFMA (tier A)
__global__ __launch_bounds__(256) void k_out_mfma(const __half* __restrict__ adjh,
                                                  const __half* __restrict__ spT,
                                                  const float* __restrict__ sp32,
                                                  const float* __restrict__ invs,
                                                  const float* __restrict__ bias,
                                                  float* __restrict__ out) {
    int nb = blockIdx.x, b = blockIdx.y, t = blockIdx.z;
    int n0 = nb * 64;
    size_t bt = (size_t)b * TT + t;
    __shared__ alignas(16) __half Al[64 * 64];
    __shared__ alignas(16) __half Bl[64 * 64];
    int wave = threadIdx.x >> 6, lane = threadIdx.x & 63;
    const __half* Ag = adjh + bt * (size_t)(NN * NN);
    const __half* Bg = spT + bt * (size_t)(64 * 1024);
    f32x4 acc[4] = {};

    for (int ch = 0; ch < 16; ++ch) {
        __syncthreads();
#pragma unroll
        for (int rep = 0; rep < 2; ++rep) {
            int idx = threadIdx.x + rep * 256;
            int r = idx >> 3, g = idx & 7;
            int gg = ch * 8 + g;
            uint4 va = {0, 0, 0, 0};
            if (n0 + r < NN && gg < 125)
                va = *(const uint4*)(Ag + (size_t)(n0 + r) * NN + gg * 8);
            *(uint4*)&Al[(r * 8 + (g ^ (r & 7))) * 8] = va;
            uint4 vb = *(const uint4*)(Bg + (size_t)r * 1024 + gg * 8);
            *(uint4*)&Bl[(r * 8 + (g ^ (r & 7))) * 8] = vb;
        }
        __syncthreads();
#pragma unroll
        for (int kc = 0; kc < 2; ++kc) {
            int ar = wave * 16 + (lane & 15);
            int ag = kc * 4 + (lane >> 4);
            f16x8 av = *(const f16x8*)&Al[(ar * 8 + (ag ^ (ar & 7))) * 8];
#pragma unroll
            for (int ct = 0; ct < 4; ++ct) {
                int br = ct * 16 + (lane & 15);
                f16x8 bv = *(const f16x8*)&Bl[(br * 8 + (ag ^ (br & 7))) * 8];
                acc[ct] = __builtin_amdgcn_mfma_f32_16x16x32_f16(av, bv, acc[ct], 0, 0, 0);
            }
        }
    }
#pragma unroll
    for (int ct = 0; ct < 4; ++ct) {
        int o = ct * 16 + (lane & 15);
        float bo = bias[o];
#pragma unroll
        for (int r = 0; r < 4; ++r) {
            int n = n0 + wave * 16 + (lane >> 4) * 4 + r;
            if (n < NN) {
                float iv = invs[bt * NN + n];
                float d = sp32[(bt * NN + n) * OO + o];
                out[(bt * NN + n) * OO + o] = fmaxf(iv * (acc[ct][r] + d) + bo, 0.f);
            }
        }
    }
}

// ---------------------------------------------------------------- k_out fp32 (tier B/C)
__global__ __launch_bounds__(256) void k_out(const float* __restrict__ adj,
                                             const float* __restrict__ sp,
                                             const float* __restrict__ invs,
                                             const float* __restrict__ bias,
                                             float* __restrict__ out) {
    int nb = blockIdx.x, b = blockIdx.y, t = blockIdx.z;
    int n0 = nb * 64;
    int cq = threadIdx.x & 15;
    int rg = threadIdx.x >> 4;
    __shared__ float spl[64][64];
    __shared__ float al[64][68];
    size_t bt = (size_t)b * TT + t;
    const float* adjp = adj + bt * (size_t)NN * NN;
    const float* spp  = sp  + bt * (size_t)NN * OO;
    float4 a0 = {0,0,0,0}, a1 = {0,0,0,0}, a2 = {0,0,0,0}, a3 = {0,0,0,0};
    for (int m0 = 0; m0 < NN; m0 += 64) {
        __syncthreads();
        for (int i = threadIdx.x; i < 1024; i += 256) {
            int r = i >> 4, c4 = (i & 15) * 4;
            int m = m0 + r;
            float4 v = (m < NN) ? *(const float4*)&spp[(size_t)m * OO + c4] : float4{0,0,0,0};
            *(float4*)&spl[r][c4] = v;
        }
        for (int i = threadIdx.x; i < 1024; i += 256) {
            int r = i >> 4, c4 = (i & 15) * 4;
            int n = n0 + r, m = m0 + c4;
            float4 v = (n < NN && m < NN) ? *(const float4*)&adjp[(size_t)n * NN + m] : float4{0,0,0,0};
            *(float4*)&al[r][c4] = v;
        }
        __syncthreads();
#pragma unroll 4
        for (int mm = 0; mm < 64; mm += 4) {
            float4 s0 = *(const float4*)&spl[mm + 0][cq * 4];
            float4 s1 = *(const float4*)&spl[mm + 1][cq * 4];
            float4 s2 = *(const float4*)&spl[mm + 2][cq * 4];
            float4 s3 = *(const float4*)&spl[mm + 3][cq * 4];
            float4 r0 = *(const float4*)&al[rg * 4 + 0][mm];
            float4 r1 = *(const float4*)&al[rg * 4 + 1][mm];
            float4 r2 = *(const float4*)&al[rg * 4 + 2][mm];
            float4 r3 = *(const float4*)&al[rg * 4 + 3][mm];
            a0.x += r0.x*s0.x + r0.y*s1.x + r0.z*s2.x + r0.w*s3.x;
            a0.y += r0.x*s0.y + r0.y*s1.y + r0.z*s2.y + r0.w*s3.y;
            a0.z += r0.x*s0.z + r0.y*s1.z + r0.z*s2.z + r0.w*s3.z;
            a0.w += r0.x*s0.w + r0.y*s1.w + r0.z*s2.w + r0.w*s3.w;
            a1.x += r1.x*s0.x + r1.y*s1.x + r1.z*s2.x + r1.w*s3.x;
            a1.y += r1.x*s0.y + r1.y*s1.y + r1.z*s2.y + r1.w*s3.y;
            a1.z += r1.x*s0.z + r1.y*s1.z + r1.z*s2.z + r1.w*s3.z;
            a1.w += r1.x*s0.w + r1.y*s1.w + r1.z*s2.w + r1.w*s3.w;
            a2.x += r2.x*s0.x + r2.y*s1.x + r2.z*s2.x + r2.w*s3.x;
            a2.y += r2.x*s0.y + r2.y*s1.y + r2.z*s2.y + r2.w*s3.y;
            a2.z += r2.x*s0.z + r2.y*s1.z + r2.z*s2.z + r2.w*s3.z;
            a2.w += r2.x*s0.w + r2.y*s1.w + r2.z*s2.w + r2.w*s3.w;
            a3.x += r3.x*s0.x + r3.y*s1.x + r3.z*s2.x + r3.w*s3.x;
            a3.y += r3.x*s0.y + r3.y*s1.y + r3.z*s2.y + r3.w*s3.y;
            a3.z += r3.x*s0.z + r3.y*s1.z + r3.z*s2.z + r3.w*s3.z;
            a3.w += r3.x*s0.w + r3.y*s1.w + r3.z*s2.w + r3.w*s3.w;
        }
    }
    float4 bias4 = *(const float4*)&bias[cq * 4];
    float4 accs[4] = {a0, a1, a2, a3};
#pragma unroll
    for (int i = 0; i < 4; ++i) {
        int n = n0 + rg * 4 + i;
        if (n < NN) {
            float iv = invs[bt * NN + n];
            float4 d = *(const float4*)&spp[(size_t)n * OO + cq * 4];
            float4 v;
            v.x = fmaxf(iv * (accs[i].x + d.x) + bias4.x, 0.f);
            v.y = fmaxf(iv * (accs[i].y + d.y) + bias4.y, 0.f);
            v.z = fmaxf(iv * (accs[i].z + d.z) + bias4.z, 0.f);
            v.w = fmaxf(iv * (accs[i].w + d.w) + bias4.w, 0.f);
            *(float4*)&out[(bt * NN + n) * OO + cq * 4] = v;
        }
    }
}

// ---------------------------------------------------------------- launch
extern "C" void kernel_launch(void* const* d_in, const int* in_sizes, int n_in,
                              void* d_out, int out_size, void* d_ws, size_t ws_size,
                              hipStream_t stream) {
    const float* x    = (const float*)d_in[0];
    const float* adj  = (const float*)d_in[1];
    const float* w_ih = (const float*)d_in[2];
    const float* w_hh = (const float*)d_in[3];
    const float* b_ih = (const float*)d_in[4];
    const float* b_hh = (const float*)d_in[5];
    const float* h0   = (const float*)d_in[6];
    const float* bias = (const float*)d_in[7];
    float* out = (float*)d_out;
    float* ws = (float*)d_ws;

    float* invs  = ws;                          // 48000
    float* summ  = invs + 48000;                // 3072
    float* gi    = summ + 3072;                 // 589824
    float* h_all = gi + 589824;                 // 13 * 16384 = 212992
    float* sp    = h_all + 212992;              // 3072000
    const size_t base_f = 3925888;              // floats
    __half* wh    = (__half*)(ws + base_f);         // 50,331,648 halves (100.7 MB)
    __half* h16   = wh + 50331648ull;               // 13 * 16384 halves
    __half* adjh  = h16 + 212992ull;                // 48,000,000 halves (96 MB)
    __half* spT   = adjh + 48000000ull;             // 3,145,728 halves (6.3 MB)
    const size_t need_B = base_f * 4 + (50331648ull + 212992ull) * 2;
    const size_t need_A = need_B + (48000000ull + 3145728ull) * 2;
    bool tierA = ws_size >= need_A;
    bool tierB = ws_size >= need_B;

    k_init_h<<<64, 256, 0, stream>>>(h0, h_all, h16);
    k_summary<<<48, 256, 0, stream>>>(x, summ);
    k_gi<<<dim3(48, 48), 256, 0, stream>>>(summ, w_ih, b_ih, gi);
    if (tierA) {
        k_conv<<<24576, 256, 0, stream>>>(w_hh, wh);       // block-linear fp32->fp16, ~6.3 TB/s
        for (int t = 0; t < TT; ++t)
            k_gstepN<<<2715, 384, 0, stream>>>(wh,
                                               h16 + (size_t)t * BB * SS,
                                               h_all + (size_t)t * BB * SS,
                                               b_hh, gi,
                                               h_all + (size_t)(t + 1) * BB * SS,
                                               h16 + (size_t)(t + 1) * BB * SS,
                                               adj, invs, adjh, t);
        k_support2<<<dim3(16, 4, 12), 256, 0, stream>>>(x, h_all, invs, sp, spT);
        k_out_mfma<<<dim3(16, 4, 12), 256, 0, stream>>>(adjh, spT, sp, invs, bias, out);
    } else if (tierB) {
        k_conv<<<24576, 256, 0, stream>>>(w_hh, wh);
        for (int t = 0; t < TT; ++t)
            k_gruN<<<1024, 384, 0, stream>>>(wh,
                                             h16 + (size_t)t * BB * SS,
                                             h_all + (size_t)t * BB * SS,
                                             b_hh, gi,
                                             h_all + (size_t)(t + 1) * BB * SS,
                                             h16 + (size_t)(t + 1) * BB * SS, t);
        k_deg<<<12000, 256, 0, stream>>>(adj, invs);
        k_support<<<dim3(16, 4, 12), 256, 0, stream>>>(x, h_all, invs, sp);
        k_out<<<dim3(16, 4, 12), 256, 0, stream>>>(adj, sp, invs, bias, out);
    } else {
        for (int t = 0; t < TT; ++t)
            k_gru<<<512, 512, 0, stream>>>(w_hh, b_hh, gi,
                                           h_all + (size_t)t * BB * SS,
                                           h_all + (size_t)(t + 1) * BB * SS, t);
        k_deg<<<12000, 256, 0, stream>>>(adj, invs);
        k_support<<<dim3(16, 4, 12), 256, 0, stream>>>(x, h_all, invs, sp);
        k_out<<<dim3(16, 4, 12), 256, 0, stream>>>(adj, sp, invs, bias, out);
    }
}

// Round 12
// 477.752 us; speedup vs baseline: 1.1432x; 1.0611x over previous
//
#include <hip/hip_runtime.h>
#include <hip/hip_fp16.h>
#include <cstdint>

#define BB 4
#define TT 12
#define NN 1000
#define FF 64
#define OO 64
#define SS 4096
#define G3 12288

typedef _Float16 f16x8 __attribute__((ext_vector_type(8)));
typedef float f32x4 __attribute__((ext_vector_type(4)));
typedef _Float16 h2v __attribute__((ext_vector_type(2)));

#if __has_builtin(__builtin_amdgcn_fdot2)
__device__ inline float fdot2(__half2 a, __half2 b, float c) {
    return __builtin_amdgcn_fdot2(*(h2v*)&a, *(h2v*)&b, c, false);
}
#else
__device__ inline float fdot2(__half2 a, __half2 b, float c) {
    float2 fa = __half22float2(a), fb = __half22float2(b);
    return fmaf(fa.x, fb.x, fmaf(fa.y, fb.y, c));
}
#endif

// ---------------------------------------------------------------- init h0 (fp32 + fp16 mirror)
__global__ void k_init_h(const float* __restrict__ h0, float* __restrict__ h_all,
                         __half* __restrict__ h16) {
    int i = blockIdx.x * 256 + threadIdx.x;
    if (i < BB * SS) {
        float v = h0[i & (SS - 1)];
        h_all[i] = v;
        h16[i] = __float2half(v);
    }
}

// ---------------------------------------------------------------- w_hh fp32 -> fp16 (block-linear stream)
__global__ void k_conv(const float* __restrict__ w, __half* __restrict__ wh) {
    size_t i = ((size_t)blockIdx.x * 256 + threadIdx.x) * 8;
    float4 a = *(const float4*)(w + i);
    float4 b = *(const float4*)(w + i + 4);
    __half2 h0 = __floats2half2_rn(a.x, a.y);
    __half2 h1 = __floats2half2_rn(a.z, a.w);
    __half2 h2 = __floats2half2_rn(b.x, b.y);
    __half2 h3 = __floats2half2_rn(b.z, b.w);
    uint4 o;
    o.x = *(const unsigned*)&h0; o.y = *(const unsigned*)&h1;
    o.z = *(const unsigned*)&h2; o.w = *(const unsigned*)&h3;
    *(uint4*)(wh + i) = o;
}

// ---------------------------------------------------------------- summary = mean_n x
__global__ void k_summary(const float* __restrict__ x, float* __restrict__ summ) {
    int bt = blockIdx.x;
    int f = threadIdx.x & 63, part = threadIdx.x >> 6;
    const float* xp = x + (size_t)bt * NN * FF;
    float s = 0.f;
    for (int n = part; n < NN; n += 4) s += xp[(size_t)n * FF + f];
    __shared__ float red[4][64];
    red[part][f] = s;
    __syncthreads();
    if (part == 0) {
        float tot = red[0][f] + red[1][f] + red[2][f] + red[3][f];
        summ[bt * FF + f] = tot * (1.0f / NN);
    }
}

// ---------------------------------------------------------------- gi = summary @ w_ih^T + b_ih
__global__ void k_gi(const float* __restrict__ summ, const float* __restrict__ w_ih,
                     const float* __restrict__ b_ih, float* __restrict__ gi) {
    int bt = blockIdx.y;
    int j = blockIdx.x * 256 + threadIdx.x;
    __shared__ float sl[64];
    if (threadIdx.x < 64) sl[threadIdx.x] = summ[bt * 64 + threadIdx.x];
    __syncthreads();
    const float* wr = w_ih + (size_t)j * 64;
    float acc = b_ih[j];
#pragma unroll
    for (int k = 0; k < 64; k += 4) {
        float4 w4 = *(const float4*)(wr + k);
        acc += sl[k] * w4.x + sl[k + 1] * w4.y + sl[k + 2] * w4.z + sl[k + 3] * w4.w;
    }
    gi[(size_t)bt * G3 + j] = acc;
}

// ---------------------------------------------------------------- deg only (tier B/C)
__global__ void k_deg(const float* __restrict__ adj, float* __restrict__ invs) {
    int row = blockIdx.x * 4 + (threadIdx.x >> 6);
    int lane = threadIdx.x & 63;
    const float* a = adj + (size_t)row * NN;
    float s = 0.f;
    for (int m = lane * 4; m < NN; m += 256) {
        float4 v = *(const float4*)(a + m);
        s += v.x + v.y + v.z + v.w;
    }
#pragma unroll
    for (int off = 32; off; off >>= 1) s += __shfl_down(s, off);
    if (lane == 0) invs[row] = rsqrtf(fmaxf(s + 1.0f, 1e-8f));
}

// ---------------------------------------------------------------- per-wave deg+conv helper (one adj row)
__device__ inline void degconv_row(const float* __restrict__ adj, float* __restrict__ invs,
                                   __half* __restrict__ adjh, int row, int lane) {
    const float* a = adj + (size_t)row * NN;
    __half* oh = adjh + (size_t)row * NN;
    float s = 0.f;
    for (int m4 = lane; m4 < 250; m4 += 64) {
        float4 v = *(const float4*)(a + m4 * 4);
        s += v.x + v.y + v.z + v.w;
        __half2 p0 = __floats2half2_rn(v.x, v.y);
        __half2 p1 = __floats2half2_rn(v.z, v.w);
        uint2 pk;
        pk.x = *(const unsigned*)&p0; pk.y = *(const unsigned*)&p1;
        *(uint2*)(oh + m4 * 4) = pk;
    }
#pragma unroll
    for (int off = 32; off; off >>= 1) s += __shfl_down(s, off);
    if (lane == 0) invs[row] = rsqrtf(fmaxf(s + 1.0f, 1e-8f));
}

// ---------------------------------------------------------------- single-pass fused GRU step:
// grid 1272 (<=1280 concurrent -> ONE occupancy pass). bx<248: deg role, waves
// grid-stride 4000 adj rows (1/12 slice). Else GRU role (1024 blocks, 6 waves =
// 2 gates x 3 parts): each wave processes rows jA=gid*2+g and jA+2048 of part p
// SEQUENTIALLY (one weight stream at a time); h16 staged in LDS once, reused.
__global__ __launch_bounds__(384) void k_gstepN(const __half* __restrict__ wh,
                                                const __half* __restrict__ h16_in,
                                                const float* __restrict__ h_in,
                                                const float* __restrict__ b_hh,
                                                const float* __restrict__ gi,
                                                float* __restrict__ h_out,
                                                __half* __restrict__ h16_out,
                                                const float* __restrict__ adj,
                                                float* __restrict__ invs,
                                                __half* __restrict__ adjh, int t) {
    __shared__ __half hl[BB * SS];                   // 32 KB
    __shared__ float sm[6][2][4];
    int bx = blockIdx.x;
    int w = threadIdx.x >> 6, lane = threadIdx.x & 63;
    if (bx < 248) {
        int dw = bx * 6 + w;                         // 0..1487
        for (int r = dw; r < 4000; r += 1488)
            degconv_row(adj, invs, adjh, t * 4000 + r, lane);
        return;
    }
    int gid = bx - 248;                              // 0..1023
    for (int i = threadIdx.x; i < 2048; i += 384)
        *(uint4*)(hl + i * 8) = *(const uint4*)(h16_in + i * 8);
    __syncthreads();

    int g = (w * 11) >> 5;                           // w/3: 0,0,0,1,1,1
    int p = w - g * 3;
    int jA = gid * 2 + g;                            // [0,2048)
    float accA[4] = {0.f, 0.f, 0.f, 0.f}, accB[4] = {0.f, 0.f, 0.f, 0.f};
    {
        const __half* wr = wh + ((size_t)p * SS + jA) * SS;
#pragma unroll 2
        for (int k0 = 0; k0 < SS; k0 += 512) {
            int k = k0 + lane * 8;
            uint4 wv = *(const uint4*)(wr + k);
            const __half2* wp = (const __half2*)&wv;
#pragma unroll
            for (int b = 0; b < 4; ++b) {
                uint4 hu = *(const uint4*)(hl + b * SS + k);
                const __half2* hp = (const __half2*)&hu;
#pragma unroll
                for (int q = 0; q < 4; ++q)
                    accA[b] = fdot2(wp[q], hp[q], accA[b]);
            }
        }
    }
    {
        const __half* wr = wh + ((size_t)p * SS + jA + 2048) * SS;
#pragma unroll 2
        for (int k0 = 0; k0 < SS; k0 += 512) {
            int k = k0 + lane * 8;
            uint4 wv = *(const uint4*)(wr + k);
            const __half2* wp = (const __half2*)&wv;
#pragma unroll
            for (int b = 0; b < 4; ++b) {
                uint4 hu = *(const uint4*)(hl + b * SS + k);
                const __half2* hp = (const __half2*)&hu;
#pragma unroll
                for (int q = 0; q < 4; ++q)
                    accB[b] = fdot2(wp[q], hp[q], accB[b]);
            }
        }
    }
#pragma unroll
    for (int b = 0; b < 4; ++b)
#pragma unroll
        for (int off = 32; off; off >>= 1) {
            accA[b] += __shfl_down(accA[b], off);
            accB[b] += __shfl_down(accB[b], off);
        }
    if (lane == 0) {
#pragma unroll
        for (int b = 0; b < 4; ++b) { sm[w][0][b] = accA[b]; sm[w][1][b] = accB[b]; }
    }
    __syncthreads();
    if (threadIdx.x < 16) {
        int rr = threadIdx.x >> 2, b = threadIdx.x & 3;
        int gg = rr & 1, sub = rr >> 1;
        int jj = gid * 2 + gg + sub * 2048;
        float hr = sm[gg * 3 + 0][sub][b], hz = sm[gg * 3 + 1][sub][b], hn = sm[gg * 3 + 2][sub][b];
        const float* gib = gi + ((size_t)b * TT + t) * G3;
        float r = 1.f / (1.f + expf(-(gib[jj] + hr + b_hh[jj])));
        float z = 1.f / (1.f + expf(-(gib[SS + jj] + hz + b_hh[SS + jj])));
        float nn = tanhf(gib[2 * SS + jj] + r * (hn + b_hh[2 * SS + jj]));
        float hv = (1.f - z) * nn + z * h_in[(size_t)b * SS + jj];
        h_out[(size_t)b * SS + jj] = hv;
        h16_out[(size_t)b * SS + jj] = __float2half(hv);
    }
}

// ---------------------------------------------------------------- unfused GRU step (tier B)
__global__ __launch_bounds__(384) void k_gruN(const __half* __restrict__ wh,
                                              const __half* __restrict__ h16_in,
                                              const float* __restrict__ h_in,
                                              const float* __restrict__ b_hh,
                                              const float* __restrict__ gi,
                                              float* __restrict__ h_out,
                                              __half* __restrict__ h16_out, int t) {
    __shared__ __half hl[BB * SS];
    __shared__ float sm[6][4];
    int w = threadIdx.x >> 6, lane = threadIdx.x & 63;
    for (int i = threadIdx.x; i < 2048; i += 384)
        *(uint4*)(hl + i * 8) = *(const uint4*)(h16_in + i * 8);
    __syncthreads();
    int g = (w * 11) >> 5;
    int p = w - g * 3;
    int j = blockIdx.x * 2 + g;
    const __half* wrow = wh + ((size_t)p * SS + j) * SS;
    float acc[4] = {0.f, 0.f, 0.f, 0.f};
#pragma unroll 2
    for (int k0 = 0; k0 < SS; k0 += 512) {
        int k = k0 + lane * 8;
        uint4 wv = *(const uint4*)(wrow + k);
        const __half2* wp = (const __half2*)&wv;
#pragma unroll
        for (int b = 0; b < 4; ++b) {
            uint4 hu = *(const uint4*)(hl + b * SS + k);
            const __half2* hp = (const __half2*)&hu;
#pragma unroll
            for (int q = 0; q < 4; ++q)
                acc[b] = fdot2(wp[q], hp[q], acc[b]);
        }
    }
#pragma unroll
    for (int b = 0; b < 4; ++b)
#pragma unroll
        for (int off = 32; off; off >>= 1)
            acc[b] += __shfl_down(acc[b], off);
    if (lane == 0) {
        sm[w][0] = acc[0]; sm[w][1] = acc[1]; sm[w][2] = acc[2]; sm[w][3] = acc[3];
    }
    __syncthreads();
    if (threadIdx.x < 8) {
        int gg = threadIdx.x >> 2, b = threadIdx.x & 3;
        int jj = blockIdx.x * 2 + gg;
        float hr = sm[gg * 3 + 0][b], hz = sm[gg * 3 + 1][b], hn = sm[gg * 3 + 2][b];
        const float* gib = gi + ((size_t)b * TT + t) * G3;
        float r = 1.f / (1.f + expf(-(gib[jj] + hr + b_hh[jj])));
        float z = 1.f / (1.f + expf(-(gib[SS + jj] + hz + b_hh[SS + jj])));
        float nn = tanhf(gib[2 * SS + jj] + r * (hn + b_hh[2 * SS + jj]));
        float hv = (1.f - z) * nn + z * h_in[(size_t)b * SS + jj];
        h_out[(size_t)b * SS + jj] = hv;
        h16_out[(size_t)b * SS + jj] = __float2half(hv);
    }
}

// ---------------------------------------------------------------- GRU step fp32 (tier C fallback)
__global__ __launch_bounds__(512) void k_gru(const float* __restrict__ w_hh,
                                             const float* __restrict__ b_hh,
                                             const float* __restrict__ gi,
                                             const float* __restrict__ h_in,
                                             float* __restrict__ h_out, int t) {
    __shared__ float hl[BB][SS];
    for (int i = threadIdx.x; i < BB * SS; i += 512)
        hl[i >> 12][i & (SS - 1)] = h_in[i];
    __syncthreads();
    int wave = threadIdx.x >> 6, lane = threadIdx.x & 63;
    int jg = blockIdx.x * 8 + wave;
    const float* r0 = w_hh + (size_t)jg * SS;
    const float* r1 = w_hh + ((size_t)SS + jg) * SS;
    const float* r2 = w_hh + ((size_t)2 * SS + jg) * SS;
    float acc[3][4] = {{0.f}};
    for (int k0 = 0; k0 < SS; k0 += 256) {
        int k = k0 + lane * 4;
        float4 w0 = *(const float4*)(r0 + k);
        float4 w1 = *(const float4*)(r1 + k);
        float4 w2 = *(const float4*)(r2 + k);
#pragma unroll
        for (int b = 0; b < 4; ++b) {
            float4 hv = *(const float4*)&hl[b][k];
            acc[0][b] += w0.x * hv.x + w0.y * hv.y + w0.z * hv.z + w0.w * hv.w;
            acc[1][b] += w1.x * hv.x + w1.y * hv.y + w1.z * hv.z + w1.w * hv.w;
            acc[2][b] += w2.x * hv.x + w2.y * hv.y + w2.z * hv.z + w2.w * hv.w;
        }
    }
#pragma unroll
    for (int p = 0; p < 3; ++p)
#pragma unroll
        for (int b = 0; b < 4; ++b)
#pragma unroll
            for (int off = 32; off; off >>= 1)
                acc[p][b] += __shfl_down(acc[p][b], off);
    if (lane == 0) {
        float br = b_hh[jg], bz = b_hh[SS + jg], bn = b_hh[2 * SS + jg];
#pragma unroll
        for (int b = 0; b < 4; ++b) {
            const float* gib = gi + ((size_t)b * TT + t) * G3;
            float r = 1.f / (1.f + expf(-(gib[jg] + acc[0][b] + br)));
            float z = 1.f / (1.f + expf(-(gib[SS + jg] + acc[1][b] + bz)));
            float nn = tanhf(gib[2 * SS + jg] + r * (acc[2][b] + bn));
            h_out[(size_t)b * SS + jg] = (1.f - z) * nn + z * hl[b][jg];
        }
    }
}

// ---------------------------------------------------------------- support (tier A): sp fp32 + spT fp16 transposed
__global__ __launch_bounds__(256) void k_support2(const float* __restrict__ x,
                                                  const float* __restrict__ h_all,
                                                  const float* __restrict__ invs,
                                                  float* __restrict__ sp,
                                                  __half* __restrict__ spT) {
    int nt = blockIdx.x, b = blockIdx.y, t = blockIdx.z;
    int n0 = nt * 64;
    int o = threadIdx.x & 63, g = threadIdx.x >> 6;
    __shared__ float wl[64][64];
    __shared__ float xl[64][64];
    __shared__ __half tl[64][72];
    for (int i = threadIdx.x; i < 64 * 72 / 2; i += 256)
        *(__half2*)&tl[0][i * 2] = __half2{};
    const float* h = h_all + ((size_t)(t + 1) * BB + b) * SS;
    for (int i = threadIdx.x; i < SS; i += 256) wl[i >> 6][i & 63] = h[i];
    const float* xp = x + ((size_t)(b * TT + t) * NN + n0) * FF;
    for (int i = threadIdx.x; i < 64 * 64; i += 256) {
        int nl = i >> 6, f = i & 63;
        xl[nl][f] = (n0 + nl < NN) ? xp[(size_t)nl * FF + f] : 0.f;
    }
    __syncthreads();
    size_t bt = (size_t)b * TT + t;
    for (int nl = g; nl < 64; nl += 4) {
        int n = n0 + nl;
        if (n >= NN) break;
        float acc = 0.f;
#pragma unroll
        for (int f = 0; f < 64; ++f) acc += xl[nl][f] * wl[f][o];
        size_t idx = bt * NN + n;
        float v = acc * invs[idx];
        sp[idx * OO + o] = v;
        tl[o][nl] = __float2half(v);
    }
    __syncthreads();
    int orow = threadIdx.x >> 2, seg = threadIdx.x & 3;
    uint4 lo = *(const uint4*)&tl[orow][seg * 16];
    uint4 hi = *(const uint4*)&tl[orow][seg * 16 + 8];
    __half* dst = spT + ((bt * 64 + orow) * 1024 + n0 + seg * 16);
    *(uint4*)dst = lo;
    *(uint4*)(dst + 8) = hi;
}

// ---------------------------------------------------------------- support (tier B/C): sp fp32 only
__global__ __launch_bounds__(256) void k_support(const float* __restrict__ x,
                                                 const float* __restrict__ h_all,
                                                 const float* __restrict__ invs,
                                                 float* __restrict__ sp) {
    int nt = blockIdx.x, b = blockIdx.y, t = blockIdx.z;
    int n0 = nt * 64;
    int o = threadIdx.x & 63, g = threadIdx.x >> 6;
    __shared__ float wl[64][64];
    __shared__ float xl[64][64];
    const float* h = h_all + ((size_t)(t + 1) * BB + b) * SS;
    for (int i = threadIdx.x; i < SS; i += 256) wl[i >> 6][i & 63] = h[i];
    const float* xp = x + ((size_t)(b * TT + t) * NN + n0) * FF;
    for (int i = threadIdx.x; i < 64 * 64; i += 256) {
        int nl = i >> 6, f = i & 63;
        xl[nl][f] = (n0 + nl < NN) ? xp[(size_t)nl * FF + f] : 0.f;
    }
    __syncthreads();
    for (int nl = g; nl < 64; nl += 4) {
        int n = n0 + nl;
        if (n >= NN) break;
        float acc = 0.f;
#pragma unroll
        for (int f = 0; f < 64; ++f) acc += xl[nl][f] * wl[f][o];
        size_t idx = ((size_t)(b * TT + t) * NN + n);
        sp[idx * OO + o] = acc * invs[idx];
    }
}

// ---------------------------------------------------------------- k_out MFMA (tier A)
__global__ __launch_bounds__(256) void k_out_mfma(const __half* __restrict__ adjh,
                                                  const __half* __restrict__ spT,
                                                  const float* __restrict__ sp32,
                                                  const float* __restrict__ invs,
                                                  const float* __restrict__ bias,
                                                  float* __restrict__ out) {
    int nb = blockIdx.x, b = blockIdx.y, t = blockIdx.z;
    int n0 = nb * 64;
    size_t bt = (size_t)b * TT + t;
    __shared__ alignas(16) __half Al[64 * 64];
    __shared__ alignas(16) __half Bl[64 * 64];
    int wave = threadIdx.x >> 6, lane = threadIdx.x & 63;
    const __half* Ag = adjh + bt * (size_t)(NN * NN);
    const __half* Bg = spT + bt * (size_t)(64 * 1024);
    f32x4 acc[4] = {};

    for (int ch = 0; ch < 16; ++ch) {
        __syncthreads();
#pragma unroll
        for (int rep = 0; rep < 2; ++rep) {
            int idx = threadIdx.x + rep * 256;
            int r = idx >> 3, g = idx & 7;
            int gg = ch * 8 + g;
            uint4 va = {0, 0, 0, 0};
            if (n0 + r < NN && gg < 125)
                va = *(const uint4*)(Ag + (size_t)(n0 + r) * NN + gg * 8);
            *(uint4*)&Al[(r * 8 + (g ^ (r & 7))) * 8] = va;
            uint4 vb = *(const uint4*)(Bg + (size_t)r * 1024 + gg * 8);
            *(uint4*)&Bl[(r * 8 + (g ^ (r & 7))) * 8] = vb;
        }
        __syncthreads();
#pragma unroll
        for (int kc = 0; kc < 2; ++kc) {
            int ar = wave * 16 + (lane & 15);
            int ag = kc * 4 + (lane >> 4);
            f16x8 av = *(const f16x8*)&Al[(ar * 8 + (ag ^ (ar & 7))) * 8];
#pragma unroll
            for (int ct = 0; ct < 4; ++ct) {
                int br = ct * 16 + (lane & 15);
                f16x8 bv = *(const f16x8*)&Bl[(br * 8 + (ag ^ (br & 7))) * 8];
                acc[ct] = __builtin_amdgcn_mfma_f32_16x16x32_f16(av, bv, acc[ct], 0, 0, 0);
            }
        }
    }
#pragma unroll
    for (int ct = 0; ct < 4; ++ct) {
        int o = ct * 16 + (lane & 15);
        float bo = bias[o];
#pragma unroll
        for (int r = 0; r < 4; ++r) {
            int n = n0 + wave * 16 + (lane >> 4) * 4 + r;
            if (n < NN) {
                float iv = invs[bt * NN + n];
                float d = sp32[(bt * NN + n) * OO + o];
                out[(bt * NN + n) * OO + o] = fmaxf(iv * (acc[ct][r] + d) + bo, 0.f);
            }
        }
    }
}

// ---------------------------------------------------------------- k_out fp32 (tier B/C)
__global__ __launch_bounds__(256) void k_out(const float* __restrict__ adj,
                                             const float* __restrict__ sp,
                                             const float* __restrict__ invs,
                                             const float* __restrict__ bias,
                                             float* __restrict__ out) {
    int nb = blockIdx.x, b = blockIdx.y, t = blockIdx.z;
    int n0 = nb * 64;
    int cq = threadIdx.x & 15;
    int rg = threadIdx.x >> 4;
    __shared__ float spl[64][64];
    __shared__ float al[64][68];
    size_t bt = (size_t)b * TT + t;
    const float* adjp = adj + bt * (size_t)NN * NN;
    const float* spp  = sp  + bt * (size_t)NN * OO;
    float4 a0 = {0,0,0,0}, a1 = {0,0,0,0}, a2 = {0,0,0,0}, a3 = {0,0,0,0};
    for (int m0 = 0; m0 < NN; m0 += 64) {
        __syncthreads();
        for (int i = threadIdx.x; i < 1024; i += 256) {
            int r = i >> 4, c4 = (i & 15) * 4;
            int m = m0 + r;
            float4 v = (m < NN) ? *(const float4*)&spp[(size_t)m * OO + c4] : float4{0,0,0,0};
            *(float4*)&spl[r][c4] = v;
        }
        for (int i = threadIdx.x; i < 1024; i += 256) {
            int r = i >> 4, c4 = (i & 15) * 4;
            int n = n0 + r, m = m0 + c4;
            float4 v = (n < NN && m < NN) ? *(const float4*)&adjp[(size_t)n * NN + m] : float4{0,0,0,0};
            *(float4*)&al[r][c4] = v;
        }
        __syncthreads();
#pragma unroll 4
        for (int mm = 0; mm < 64; mm += 4) {
            float4 s0 = *(const float4*)&spl[mm + 0][cq * 4];
            float4 s1 = *(const float4*)&spl[mm + 1][cq * 4];
            float4 s2 = *(const float4*)&spl[mm + 2][cq * 4];
            float4 s3 = *(const float4*)&spl[mm + 3][cq * 4];
            float4 r0 = *(const float4*)&al[rg * 4 + 0][mm];
            float4 r1 = *(const float4*)&al[rg * 4 + 1][mm];
            float4 r2 = *(const float4*)&al[rg * 4 + 2][mm];
            float4 r3 = *(const float4*)&al[rg * 4 + 3][mm];
            a0.x += r0.x*s0.x + r0.y*s1.x + r0.z*s2.x + r0.w*s3.x;
            a0.y += r0.x*s0.y + r0.y*s1.y + r0.z*s2.y + r0.w*s3.y;
            a0.z += r0.x*s0.z + r0.y*s1.z + r0.z*s2.z + r0.w*s3.z;
            a0.w += r0.x*s0.w + r0.y*s1.w + r0.z*s2.w + r0.w*s3.w;
            a1.x += r1.x*s0.x + r1.y*s1.x + r1.z*s2.x + r1.w*s3.x;
            a1.y += r1.x*s0.y + r1.y*s1.y + r1.z*s2.y + r1.w*s3.y;
            a1.z += r1.x*s0.z + r1.y*s1.z + r1.z*s2.z + r1.w*s3.z;
            a1.w += r1.x*s0.w + r1.y*s1.w + r1.z*s2.w + r1.w*s3.w;
            a2.x += r2.x*s0.x + r2.y*s1.x + r2.z*s2.x + r2.w*s3.x;
            a2.y += r2.x*s0.y + r2.y*s1.y + r2.z*s2.y + r2.w*s3.y;
            a2.z += r2.x*s0.z + r2.y*s1.z + r2.z*s2.z + r2.w*s3.z;
            a2.w += r2.x*s0.w + r2.y*s1.w + r2.z*s2.w + r2.w*s3.w;
            a3.x += r3.x*s0.x + r3.y*s1.x + r3.z*s2.x + r3.w*s3.x;
            a3.y += r3.x*s0.y + r3.y*s1.y + r3.z*s2.y + r3.w*s3.y;
            a3.z += r3.x*s0.z + r3.y*s1.z + r3.z*s2.z + r3.w*s3.z;
            a3.w += r3.x*s0.w + r3.y*s1.w + r3.z*s2.w + r3.w*s3.w;
        }
    }
    float4 bias4 = *(const float4*)&bias[cq * 4];
    float4 accs[4] = {a0, a1, a2, a3};
#pragma unroll
    for (int i = 0; i < 4; ++i) {
        int n = n0 + rg * 4 + i;
        if (n < NN) {
            float iv = invs[bt * NN + n];
            float4 d = *(const float4*)&spp[(size_t)n * OO + cq * 4];
            float4 v;
            v.x = fmaxf(iv * (accs[i].x + d.x) + bias4.x, 0.f);
            v.y = fmaxf(iv * (accs[i].y + d.y) + bias4.y, 0.f);
            v.z = fmaxf(iv * (accs[i].z + d.z) + bias4.z, 0.f);
            v.w = fmaxf(iv * (accs[i].w + d.w) + bias4.w, 0.f);
            *(float4*)&out[(bt * NN + n) * OO + cq * 4] = v;
        }
    }
}

// ---------------------------------------------------------------- launch
extern "C" void kernel_launch(void* const* d_in, const int* in_sizes, int n_in,
                              void* d_out, int out_size, void* d_ws, size_t ws_size,
                              hipStream_t stream) {
    const float* x    = (const float*)d_in[0];
    const float* adj  = (const float*)d_in[1];
    const float* w_ih = (const float*)d_in[2];
    const float* w_hh = (const float*)d_in[3];
    const float* b_ih = (const float*)d_in[4];
    const float* b_hh = (const float*)d_in[5];
    const float* h0   = (const float*)d_in[6];
    const float* bias = (const float*)d_in[7];
    float* out = (float*)d_out;
    float* ws = (float*)d_ws;

    float* invs  = ws;                          // 48000
    float* summ  = invs + 48000;                // 3072
    float* gi    = summ + 3072;                 // 589824
    float* h_all = gi + 589824;                 // 13 * 16384 = 212992
    float* sp    = h_all + 212992;              // 3072000
    const size_t base_f = 3925888;              // floats
    __half* wh    = (__half*)(ws + base_f);         // 50,331,648 halves (100.7 MB)
    __half* h16   = wh + 50331648ull;               // 13 * 16384 halves
    __half* adjh  = h16 + 212992ull;                // 48,000,000 halves (96 MB)
    __half* spT   = adjh + 48000000ull;             // 3,145,728 halves (6.3 MB)
    const size_t need_B = base_f * 4 + (50331648ull + 212992ull) * 2;
    const size_t need_A = need_B + (48000000ull + 3145728ull) * 2;
    bool tierA = ws_size >= need_A;
    bool tierB = ws_size >= need_B;

    k_init_h<<<64, 256, 0, stream>>>(h0, h_all, h16);
    k_summary<<<48, 256, 0, stream>>>(x, summ);
    k_gi<<<dim3(48, 48), 256, 0, stream>>>(summ, w_ih, b_ih, gi);
    if (tierA) {
        k_conv<<<24576, 256, 0, stream>>>(w_hh, wh);       // block-linear fp32->fp16
        for (int t = 0; t < TT; ++t)
            k_gstepN<<<1272, 384, 0, stream>>>(wh,
                                               h16 + (size_t)t * BB * SS,
                                               h_all + (size_t)t * BB * SS,
                                               b_hh, gi,
                                               h_all + (size_t)(t + 1) * BB * SS,
                                               h16 + (size_t)(t + 1) * BB * SS,
                                               adj, invs, adjh, t);
        k_support2<<<dim3(16, 4, 12), 256, 0, stream>>>(x, h_all, invs, sp, spT);
        k_out_mfma<<<dim3(16, 4, 12), 256, 0, stream>>>(adjh, spT, sp, invs, bias, out);
    } else if (tierB) {
        k_conv<<<24576, 256, 0, stream>>>(w_hh, wh);
        for (int t = 0; t < TT; ++t)
            k_gruN<<<1024, 384, 0, stream>>>(wh,
                                             h16 + (size_t)t * BB * SS,
                                             h_all + (size_t)t * BB * SS,
                                             b_hh, gi,
                                             h_all + (size_t)(t + 1) * BB * SS,
                                             h16 + (size_t)(t + 1) * BB * SS, t);
        k_deg<<<12000, 256, 0, stream>>>(adj, invs);
        k_support<<<dim3(16, 4, 12), 256, 0, stream>>>(x, h_all, invs, sp);
        k_out<<<dim3(16, 4, 12), 256, 0, stream>>>(adj, sp, invs, bias, out);
    } else {
        for (int t = 0; t < TT; ++t)
            k_gru<<<512, 512, 0, stream>>>(w_hh, b_hh, gi,
                                           h_all + (size_t)t * BB * SS,
                                           h_all + (size_t)(t + 1) * BB * SS, t);
        k_deg<<<12000, 256, 0, stream>>>(adj, invs);
        k_support<<<dim3(16, 4, 12), 256, 0, stream>>>(x, h_all, invs, sp);
        k_out<<<dim3(16, 4, 12), 256, 0, stream>>>(adj, sp, invs, bias, out);
    }
}